// Round 6
// baseline (339.670 us; speedup 1.0000x reference)
//
#include <hip/hip_runtime.h>

// SmartDerivatives: out[b, a*3+dim] = (segment_sum(left * x[b,des]))^2
// Deterministic triu_indices(100,1) scatter; index arrays never read.
//
// R5 (zero-atomic, lane=column-j register accumulation + DPP row reduction)
// cut 110 -> ~60us. Remaining gap vs 22.5us HBM floor blamed on 24B-strided
// global float2 loads (3x L1 transactions, exposed latency).
// R6: rows are contiguous in memory -> stage each 8-row group (<=18.4 KB,
// one row per wave) into LDS with dense float4 loads by all 512 threads;
// compute reads LDS (strided there is cheap). Still zero atomics.

#define N_ATOMS  100
#define D_DESC   4950
#define BATCH    1024
#define NOUT     300
#define NWAVES   8
#define NGROUP   13          // ceil(99 rows / 8)
#define STAGE_F4 1147        // group 0 needs 1146 float4s (rows 0..7)

__device__ __forceinline__ int rowstart(int i) {
    // triu(100,1): sum_{k<i}(99-k) = i*(199-i)/2
    return (i * (199 - i)) >> 1;
}

// one DPP reduce step: v += dpp_shuffled(v), zero-filled OOB
template<int CTRL, int RMASK>
__device__ __forceinline__ float dpp_step(float v) {
    int s = __builtin_amdgcn_update_dpp(0, __float_as_int(v), CTRL, RMASK, 0xf, true);
    return v + __int_as_float(s);
}
// full 64-lane sum; result valid in lane 63. VALU-pipe only.
__device__ __forceinline__ float wave_sum(float v) {
    v = dpp_step<0x111, 0xf>(v);   // row_shr:1
    v = dpp_step<0x112, 0xf>(v);   // row_shr:2
    v = dpp_step<0x114, 0xf>(v);   // row_shr:4
    v = dpp_step<0x118, 0xf>(v);   // row_shr:8
    v = dpp_step<0x142, 0xa>(v);   // row_bcast:15
    v = dpp_step<0x143, 0xc>(v);   // row_bcast:31 -> lane63 = total
    return v;
}

__global__ __launch_bounds__(512, 8)
void sd_kernel(const float* __restrict__ x,
               const float* __restrict__ left,
               float* __restrict__ out) {
    __shared__ float4 stage[STAGE_F4];      // 8-row group of `left`, dense-staged
    __shared__ float  rowacc[NOUT];         // row (i-part) sums, uniquely written
    __shared__ float  part[NWAVES][NOUT];   // per-wave column (j-part) partials
    const int b    = blockIdx.x;
    const int tid  = threadIdx.x;
    const int w    = tid >> 6;
    const int lane = tid & 63;

    for (int t = tid; t < NOUT; t += 512) rowacc[t] = 0.0f;  // atom 99 row = 0

    const float*  __restrict__ xb  = x + (size_t)b * D_DESC;
    const float4* __restrict__ lb4 = (const float4*)(left + (size_t)b * D_DESC * 6);

    // lane l owns output columns j=l (a*) and j=64+l (b*, l<36)
    float a0 = 0.f, a1 = 0.f, a2 = 0.f;
    float b0 = 0.f, b1 = 0.f, b2 = 0.f;

    for (int g = 0; g < NGROUP; ++g) {
        const int i0  = g * NWAVES;
        const int rs0 = rowstart(i0);
        const int rs8 = rowstart(min(i0 + NWAVES, N_ATOMS - 1));
        // float4 range covering floats [rs0*6, rs8*6)
        const int f0 = (rs0 * 3) >> 1;          // floor(rs0*1.5)
        const int f1 = (rs8 * 3 + 1) >> 1;      // ceil(rs8*1.5)
        for (int f = f0 + tid; f < f1; f += 512) stage[f - f0] = lb4[f];
        __syncthreads();

        const int i = i0 + w;                   // this wave's row
        if (i < N_ATOMS - 1) {
            const int rs = rowstart(i);
            const float* __restrict__ rowl = (const float*)stage + (rs * 6 - f0 * 4);
            float s0 = 0.f, s1 = 0.f, s2 = 0.f;

            if (i < 63) {   // wave-uniform: some column j in [0,64) has j>i
                const int  j = lane;
                const bool v = j > i;
                const int  doff = v ? (j - i - 1) : 0;        // clamp: valid addr
                const float2* lp = (const float2*)(rowl + doff * 6);
                const float2 c01 = lp[0], c23 = lp[1], c45 = lp[2];
                const float  m   = v ? xb[rs + doff] : 0.f;   // dense 4B global
                s0 += c01.x * m;  s1 += c01.y * m;  s2 += c23.x * m;   // row i
                a0 += c23.y * m;  a1 += c45.x * m;  a2 += c45.y * m;   // col j
            }
            {   // columns j in [64,100)
                const int  j = 64 + lane;
                const bool v = (j < N_ATOMS) && (j > i);
                const int  doff = v ? (j - i - 1) : 0;
                const float2* lp = (const float2*)(rowl + doff * 6);
                const float2 c01 = lp[0], c23 = lp[1], c45 = lp[2];
                const float  m   = v ? xb[rs + doff] : 0.f;
                s0 += c01.x * m;  s1 += c01.y * m;  s2 += c23.x * m;
                b0 += c23.y * m;  b1 += c45.x * m;  b2 += c45.y * m;
            }

            s0 = wave_sum(s0);
            s1 = wave_sum(s1);
            s2 = wave_sum(s2);
            if (lane == 63) {       // row i owned by exactly one wave: plain store
                rowacc[i * 3 + 0] = s0;
                rowacc[i * 3 + 1] = s1;
                rowacc[i * 3 + 2] = s2;
            }
        }
        __syncthreads();            // protect stage[] before next group's writes
    }

    // per-wave column partials (plain stores, disjoint slices)
    part[w][lane * 3 + 0] = a0;
    part[w][lane * 3 + 1] = a1;
    part[w][lane * 3 + 2] = a2;
    if (lane < N_ATOMS - 64) {
        part[w][(64 + lane) * 3 + 0] = b0;
        part[w][(64 + lane) * 3 + 1] = b1;
        part[w][(64 + lane) * 3 + 2] = b2;
    }
    __syncthreads();

    // epilogue: total = rowsum + 8 column partials; square; coalesced store
    float* __restrict__ ob = out + (size_t)b * NOUT;
    for (int t = tid; t < NOUT; t += 512) {
        float v = rowacc[t];
        #pragma unroll
        for (int q = 0; q < NWAVES; ++q) v += part[q][t];
        ob[t] = v * v;
    }
}

extern "C" void kernel_launch(void* const* d_in, const int* in_sizes, int n_in,
                              void* d_out, int out_size, void* d_ws, size_t ws_size,
                              hipStream_t stream) {
    const float* x    = (const float*)d_in[0];   // [BATCH, D]
    const float* left = (const float*)d_in[1];   // [BATCH*D*6]
    float* out = (float*)d_out;                  // [BATCH, 300]
    sd_kernel<<<BATCH, 512, 0, stream>>>(x, left, out);
}

// Round 7
// 333.300 us; speedup vs baseline: 1.0191x; 1.0191x over previous
//
#include <hip/hip_runtime.h>

// SmartDerivatives: out[b, a*3+dim] = (segment_sum(left * x[b,des]))^2
// Deterministic triu_indices(100,1) scatter; index arrays never read.
//
// R7: R5/R6 (~60us) were bound by the per-group DPP reductions + strided
// access pattern, not HBM (floor 22.5us). New structure: block = (frame,
// half-triangle-by-rows); stage the half-frame (left 59.6KB + x 10KB) into
// LDS with dense float4/float2 bulk loads; ONE barrier; each thread owns
// (atom a, dim c, 1/3-chunk) and serially register-accumulates its row-part
// (contiguous) + col-part (incremental d += 98-i). Zero atomics, zero wave
// reductions. Partials -> ws, combine kernel squares.

#define N_ATOMS 100
#define D_DESC  4950
#define BATCH   1024
#define NOUT    300

// sub 0: rows 0..28  -> descs [0,2465)   -> left float4 [0,3698),    x float2 [0,1233)
// sub 1: rows 29..98 -> descs [2465,4950)-> left float4 [3697,7425), x float2 [1232,2475)
#define SL4_MAX 3728
#define SX2_MAX 1243

__device__ __forceinline__ int rowstart(int i) { return (i * (199 - i)) >> 1; }

__global__ __launch_bounds__(1024, 8)
void sd_partial_kernel(const float* __restrict__ x,
                       const float* __restrict__ left,
                       float* __restrict__ ws) {
    __shared__ float4 sl4[SL4_MAX];   // left chunk, dense-staged
    __shared__ float2 sx2[SX2_MAX];   // x chunk
    __shared__ float  spart[1024];

    const int b   = blockIdx.x >> 1;
    const int sub = blockIdx.x & 1;
    const int tid = threadIdx.x;

    const int r0      = sub ? 29   : 0;     // row range [r0, r1)
    const int r1      = sub ? 99   : 29;
    const int f4start = sub ? 3697 : 0;     // left float4 range
    const int f4cnt   = sub ? 3728 : 3698;
    const int x2start = sub ? 1232 : 0;     // x float2 range
    const int x2cnt   = sub ? 1243 : 1233;
    const int lbase   = f4start * 4;        // float offset of sl4[0] in frame
    const int xbase   = x2start * 2;        // float offset of sx2[0] in frame

    // ---- bulk stage: dense, 4 (and 2) outstanding loads per thread
    const float4* __restrict__ lb4 =
        (const float4*)(left + (size_t)b * (D_DESC * 6)) + f4start;
    const float2* __restrict__ xb2 =
        (const float2*)(x + (size_t)b * D_DESC) + x2start;

    float4 r4[4];
    #pragma unroll
    for (int k = 0; k < 4; ++k) {
        int idx = tid + k * 1024;
        r4[k] = lb4[idx < f4cnt ? idx : f4cnt - 1];   // clamped: no divergence
    }
    float2 r2[2];
    #pragma unroll
    for (int k = 0; k < 2; ++k) {
        int idx = tid + k * 1024;
        r2[k] = xb2[idx < x2cnt ? idx : x2cnt - 1];
    }
    #pragma unroll
    for (int k = 0; k < 4; ++k) {
        int idx = tid + k * 1024;
        if (idx < f4cnt) sl4[idx] = r4[k];
    }
    #pragma unroll
    for (int k = 0; k < 2; ++k) {
        int idx = tid + k * 1024;
        if (idx < x2cnt) sx2[idx] = r2[k];
    }
    __syncthreads();

    const float* __restrict__ sl = (const float*)sl4;
    const float* __restrict__ sx = (const float*)sx2;

    // ---- compute: thread t<900 owns output o=t/3 (a=o/3, c=o%3), chunk q=t%3
    float s = 0.0f;
    if (tid < 900) {
        const int o = tid / 3;
        const int q = tid - 3 * o;
        const int a = o / 3;
        const int c = o - 3 * a;

        // row part: a's own row (contiguous descriptors), if in this block
        if (a >= r0 && a < r1) {
            const int rs  = rowstart(a);
            const int len = 99 - a;
            const float* __restrict__ Lr = sl + (rs * 6 - lbase) + c;
            const float* __restrict__ Xr = sx + (rs - xbase);
            for (int m = q; m < len; m += 3)
                s += Lr[m * 6] * Xr[m];
        }
        // col part: rows i in [r0, min(a,r1)); d(i,a) = rowstart(i)+a-i-1
        int i = r0 + q;
        const int iend = (a < r1) ? a : r1;
        if (i < iend) {
            int d    = rowstart(i) + a - i - 1;
            int step = 291 - 3 * i;            // d(i+3,a) - d(i,a)
            while (true) {
                s += sl[d * 6 + 3 + c - lbase] * sx[d - xbase];
                i += 3;
                if (i >= iend) break;
                d += step;
                step -= 9;
            }
        }
    }
    spart[tid] = s;
    __syncthreads();

    // ---- 3-way combine, write partial to ws[sub][b][o]
    if (tid < NOUT) {
        const float p = spart[3 * tid] + spart[3 * tid + 1] + spart[3 * tid + 2];
        ws[((size_t)sub * BATCH + b) * NOUT + tid] = p;
    }
}

// out = (ws0 + ws1)^2, float4-vectorized. 307200 floats = 76800 float4s.
__global__ __launch_bounds__(256)
void sd_combine_kernel(const float* __restrict__ ws, float* __restrict__ out) {
    const int idx = blockIdx.x * 256 + threadIdx.x;
    const float4 u = ((const float4*)ws)[idx];
    const float4 v = ((const float4*)(ws + (size_t)BATCH * NOUT))[idx];
    float4 o;
    o.x = u.x + v.x; o.x *= o.x;
    o.y = u.y + v.y; o.y *= o.y;
    o.z = u.z + v.z; o.z *= o.z;
    o.w = u.w + v.w; o.w *= o.w;
    ((float4*)out)[idx] = o;
}

extern "C" void kernel_launch(void* const* d_in, const int* in_sizes, int n_in,
                              void* d_out, int out_size, void* d_ws, size_t ws_size,
                              hipStream_t stream) {
    const float* x    = (const float*)d_in[0];   // [BATCH, D]
    const float* left = (const float*)d_in[1];   // [BATCH*D*6]
    float* ws  = (float*)d_ws;                   // 2*1024*300 floats = 2.46 MB
    float* out = (float*)d_out;                  // [BATCH, 300]

    sd_partial_kernel<<<BATCH * 2, 1024, 0, stream>>>(x, left, ws);
    sd_combine_kernel<<<(BATCH * NOUT / 4) / 256, 256, 0, stream>>>(ws, out);
}

// Round 8
// 332.455 us; speedup vs baseline: 1.0217x; 1.0025x over previous
//
#include <hip/hip_runtime.h>

// SmartDerivatives: out[b, a*3+dim] = (segment_sum(left * x[b,des]))^2
// Deterministic triu_indices(100,1) scatter; index arrays never read.
//
// R8: R5-R7 all ~56-60us. Model: staging (22.5us HBM floor) + ~23us of LDS
// compute reads (59,400 b32 lane-reads/frame, 2 per MAC) poorly overlapped.
// Fix: stage z = left*x (multiply fused into the dense float4 staging pass;
// x read from global/L2 there) -> compute halves to 24,750 lane-reads/frame
// (row: float2+b32, col: 3xb32, no x reads), hidden under the other resident
// block's staging. Zero atomics, one barrier phase, partials -> ws + combine.

#define N_ATOMS 100
#define D_DESC  4950
#define BATCH   1024
#define NOUT    300

// sub 0: rows 0..28  -> descs [0,2465)    -> float4 [0,3698)
// sub 1: rows 29..98 -> descs [2465,4950) -> float4 [3697,7425)
#define SZ4_MAX 3728

__device__ __forceinline__ int rowstart(int i) { return (i * (199 - i)) >> 1; }

__global__ __launch_bounds__(1024, 8)
void sd_partial_kernel(const float* __restrict__ x,
                       const float* __restrict__ left,
                       float* __restrict__ ws) {
    __shared__ float4 sz4[SZ4_MAX];       // z = left*x, dense-staged
    __shared__ float  spart[NOUT][8];     // [output][6 partials + pad]

    const int b   = blockIdx.x >> 1;
    const int sub = blockIdx.x & 1;
    const int tid = threadIdx.x;

    const int f4start = sub ? 3697 : 0;
    const int f4cnt   = sub ? 3728 : 3698;
    const int zb      = f4start * 4;      // float offset of sz4[0] in frame
    const int r0      = sub ? 29 : 0;     // rows [r0, r1) staged in this block
    const int r1      = sub ? 99 : 29;

    for (int t = tid; t < NOUT * 8; t += 1024) ((float*)spart)[t] = 0.0f;

    const float4* __restrict__ lb4 =
        (const float4*)(left + (size_t)b * (D_DESC * 6)) + f4start;
    const float* __restrict__ xb = x + (size_t)b * D_DESC;

    // ---- stage z: dense float4 left-loads, fused multiply by x (from L2).
    // float4 idx covers frame floats g..g+3, g = (f4start+idx)*4; element e
    // has channel (g+e)%6 of descriptor (g+e)/6; r = g%6 in {0,2,4}; only
    // r==4 straddles two descriptors (elements 2,3 -> d0+1).
    #pragma unroll
    for (int k = 0; k < 4; ++k) {
        const int idx = tid + k * 1024;
        if (idx < f4cnt) {
            const float4 L = lb4[idx];
            const int g  = (f4start + idx) * 4;
            const int d0 = g / 6;
            const int r  = g - 6 * d0;
            const float x0 = xb[d0];
            const float x1 = xb[(g + 3) / 6];   // == x0 unless r==4
            float4 z;
            z.x = L.x * x0;
            z.y = L.y * x0;
            z.z = L.z * ((r + 2 >= 6) ? x1 : x0);
            z.w = L.w * ((r + 3 >= 6) ? x1 : x0);
            sz4[idx] = z;
        }
    }
    __syncthreads();

    const float* __restrict__ sz = (const float*)sz4;
    const int nr = r1 - r0;

    // ---- row part: thread (a, q): sum channels 0..2 over row a's descs
    if (tid < 3 * nr) {
        const int a  = r0 + tid / 3;
        const int q  = tid - 3 * (tid / 3);
        const int rs = rowstart(a);
        const int len = 99 - a;
        const float* __restrict__ base = sz + (rs * 6 - zb);
        float s0 = 0.f, s1 = 0.f, s2 = 0.f;
        for (int m = q; m < len; m += 3) {
            const float2 c01 = *(const float2*)(base + m * 6);  // 8B-aligned
            const float  c2  = base[m * 6 + 2];
            s0 += c01.x; s1 += c01.y; s2 += c2;
        }
        spart[a * 3 + 0][q] = s0;
        spart[a * 3 + 1][q] = s1;
        spart[a * 3 + 2][q] = s2;
    }

    // ---- col part: thread (j, q): sum channels 3..5 over column j's descs
    // with rows i in [r0, min(j,r1)); d(i,j) = rowstart(i)+j-i-1, incremental.
    const int cbase = 3 * nr;
    const int nc    = sub ? 70 : 99;
    const int j0    = sub ? 30 : 1;
    const int t2    = tid - cbase;
    if (t2 >= 0 && t2 < 3 * nc) {
        const int j = j0 + t2 / 3;
        const int q = t2 - 3 * (t2 / 3);
        float s3 = 0.f, s4 = 0.f, s5 = 0.f;
        int i = r0 + q;
        const int iend = (j < r1) ? j : r1;
        if (i < iend) {
            int d    = rowstart(i) + j - i - 1;
            int step = 291 - 3 * i;            // d(i+3,j) - d(i,j)
            while (true) {
                const int f = d * 6 + 3 - zb;
                s3 += sz[f]; s4 += sz[f + 1]; s5 += sz[f + 2];
                i += 3;
                if (i >= iend) break;
                d += step; step -= 9;
            }
        }
        spart[j * 3 + 0][3 + q] = s3;
        spart[j * 3 + 1][3 + q] = s4;
        spart[j * 3 + 2][3 + q] = s5;
    }
    __syncthreads();

    // ---- combine 6 partials per output, write to ws[sub][b][o]
    if (tid < NOUT) {
        const float* p = spart[tid];
        ws[((size_t)sub * BATCH + b) * NOUT + tid] =
            p[0] + p[1] + p[2] + p[3] + p[4] + p[5];
    }
}

// out = (ws0 + ws1)^2, float4-vectorized. 307200 floats = 76800 float4s.
__global__ __launch_bounds__(256)
void sd_combine_kernel(const float* __restrict__ ws, float* __restrict__ out) {
    const int idx = blockIdx.x * 256 + threadIdx.x;
    const float4 u = ((const float4*)ws)[idx];
    const float4 v = ((const float4*)(ws + (size_t)BATCH * NOUT))[idx];
    float4 o;
    o.x = u.x + v.x; o.x *= o.x;
    o.y = u.y + v.y; o.y *= o.y;
    o.z = u.z + v.z; o.z *= o.z;
    o.w = u.w + v.w; o.w *= o.w;
    ((float4*)out)[idx] = o;
}

extern "C" void kernel_launch(void* const* d_in, const int* in_sizes, int n_in,
                              void* d_out, int out_size, void* d_ws, size_t ws_size,
                              hipStream_t stream) {
    const float* x    = (const float*)d_in[0];   // [BATCH, D]
    const float* left = (const float*)d_in[1];   // [BATCH*D*6]
    float* ws  = (float*)d_ws;                   // 2*1024*300 floats = 2.46 MB
    float* out = (float*)d_out;                  // [BATCH, 300]

    sd_partial_kernel<<<BATCH * 2, 1024, 0, stream>>>(x, left, ws);
    sd_combine_kernel<<<(BATCH * NOUT / 4) / 256, 256, 0, stream>>>(ws, out);
}